// Round 9
// baseline (6321.525 us; speedup 1.0000x reference)
//
#include <hip/hip_runtime.h>
#include <hip/hip_bf16.h>

#define VV 50257
#define DD 512
#define TT 1024
#define VPADN 50304   // 393*128
#define NBR 64        // recurrence blocks, 8 h-dims each
#define WCB 128       // extra blocks doing W_out conversion concurrently

typedef __bf16 bf16;
typedef __attribute__((ext_vector_type(8))) __bf16 bf16x8;
typedef __attribute__((ext_vector_type(4))) __bf16 bf16x4;
typedef __attribute__((ext_vector_type(4))) float f32x4;
typedef __attribute__((ext_vector_type(4))) unsigned int u32x4;

__device__ __forceinline__ void gload_lds16(const void* g, void* l) {
  __builtin_amdgcn_global_load_lds(
      (__attribute__((address_space(1))) void*)(void*)g,
      (__attribute__((address_space(3))) void*)l, 16, 0, 0);
}

__device__ __forceinline__ unsigned umin2(unsigned a, unsigned b) { return a < b ? a : b; }

// ---------------- phase 1: sequential LSTM recurrence (blocks 0..63)
//                  + W_out f32->bf16 conversion (blocks 64..191, concurrent) --------------
// Block b<64 owns dims [b*8, b*8+8); wave w owns dim hd=b*8+w. NO per-step barrier:
// each wave polls the full h-vector it needs directly into registers (4 dwordx4 of
// packed (stamp|bits) u64s, sc1). Polls for h_t are issued at the END of step t,
// AFTER the publish stores (FIFO vmcnt -> store-ack overlaps poll RT; next step's
// vmcnt(0) waits only for poll data). Merged butterfly reduce: 7 shfls for all 4 gates.
__global__ __launch_bounds__(512) __attribute__((amdgpu_waves_per_eu(2, 2)))
void recur_fused_kernel(
    const int* __restrict__ idx,
    const float* __restrict__ Wii, const float* __restrict__ Wif,
    const float* __restrict__ Wio, const float* __restrict__ Wig,
    const float* __restrict__ Whi, const float* __restrict__ Whf,
    const float* __restrict__ Who, const float* __restrict__ Whg,
    const float* __restrict__ bi, const float* __restrict__ bfv,
    const float* __restrict__ bo, const float* __restrict__ bg,
    const float* __restrict__ Wout,
    unsigned long long* __restrict__ Hpack, bf16* __restrict__ Hbf,
    bf16* __restrict__ Wbf, float* __restrict__ out_tail) {
  __shared__ int idxs[TT];
  const int b = blockIdx.x, tid = threadIdx.x;

  if (b >= NBR) {            // ---- concurrent W_out conversion ----
    const int wb = b - NBR;
    const size_t nch = (size_t)VPADN * DD / 4;
    for (size_t i = (size_t)wb * 512 + tid; i < nch; i += (size_t)WCB * 512) {
      size_t e = i << 2;
      bf16x4 o;
      if ((e >> 9) < VV) {
        f32x4 x = *(const f32x4*)&Wout[e];
        o[0] = (bf16)x[0]; o[1] = (bf16)x[1]; o[2] = (bf16)x[2]; o[3] = (bf16)x[3];
      } else {
        o[0] = o[1] = o[2] = o[3] = (bf16)0.f;
      }
      *(bf16x4*)&Wbf[e] = o;
    }
    return;
  }

  idxs[tid] = idx[tid];
  idxs[tid + 512] = idx[tid + 512];

  const int lane = tid & 63, w = tid >> 6;
  const int hd = (b << 3) + w;

  // per-thread register weights: 4 gates x 2 half-rows (32 VGPRs)
  f32x4 wr0[4], wr1[4];
  {
    #pragma unroll
    for (int g = 0; g < 4; ++g) {
      const float* Wg = (g == 0) ? Whi : (g == 1) ? Whf : (g == 2) ? Who : Whg;
      wr0[g] = *(const f32x4*)&Wg[(size_t)hd*DD + (lane << 2)];
      wr1[g] = *(const f32x4*)&Wg[(size_t)hd*DD + 256 + (lane << 2)];
    }
  }
  #pragma unroll
  for (int g = 0; g < 4; ++g) {
    asm volatile("" : "+v"(wr0[g]));
    asm volatile("" : "+v"(wr1[g]));
  }

  // lanes 0..3 gather gate (=lane) input column; bias broadcast to every lane once
  const float* wxp = nullptr;
  float bias = 0.f;
  if (lane < 4) {
    const float* Wx = (lane == 0) ? Wii : (lane == 1) ? Wif : (lane == 2) ? Wio : Wig;
    const float* bx = (lane == 0) ? bi : (lane == 1) ? bfv : (lane == 2) ? bo : bg;
    wxp = &Wx[(size_t)hd * VV];
    bias = bx[hd];
  }
  float c = 0.f, hout = 0.f;
  __syncthreads();   // idxs ready (only barrier in the kernel)

  const float bias_my = __shfl(bias, lane & 3);
  float xv_cur = 0.f;
  if (lane < 4) xv_cur = wxp[idxs[0]];

  u32x4 p0, p1, p2, p3;
  const unsigned long long* lo = nullptr;
  const unsigned long long* hi = nullptr;
  f32x4 h0 = {0.f, 0.f, 0.f, 0.f}, h1 = {0.f, 0.f, 0.f, 0.f};

  for (int t = 0; t < TT; ++t) {
    if (t > 0) {
      asm volatile("s_waitcnt vmcnt(0)" ::: "memory");
      __builtin_amdgcn_sched_barrier(0);
      unsigned mn = umin2(umin2(umin2(p0[1], p0[3]), umin2(p1[1], p1[3])),
                          umin2(umin2(p2[1], p2[3]), umin2(p3[1], p3[3])));
      while (__builtin_expect(mn != (unsigned)t, 0)) {
        asm volatile("global_load_dwordx4 %0, %4, off sc1\n\t"
                     "global_load_dwordx4 %1, %4, off offset:16 sc1\n\t"
                     "global_load_dwordx4 %2, %5, off sc1\n\t"
                     "global_load_dwordx4 %3, %5, off offset:16 sc1\n\t"
                     "s_waitcnt vmcnt(0)"
                     : "=&v"(p0), "=&v"(p1), "=&v"(p2), "=&v"(p3)
                     : "v"(lo), "v"(hi) : "memory");
        __builtin_amdgcn_sched_barrier(0);
        mn = umin2(umin2(umin2(p0[1], p0[3]), umin2(p1[1], p1[3])),
                   umin2(umin2(p2[1], p2[3]), umin2(p3[1], p3[3])));
      }
      h0[0] = __uint_as_float(p0[0]); h0[1] = __uint_as_float(p0[2]);
      h0[2] = __uint_as_float(p1[0]); h0[3] = __uint_as_float(p1[2]);
      h1[0] = __uint_as_float(p2[0]); h1[1] = __uint_as_float(p2[2]);
      h1[2] = __uint_as_float(p3[0]); h1[3] = __uint_as_float(p3[2]);
    }

    // 4 gate partial dots (cols 4l..4l+3, 256+4l..256+4l+3)
    f32x4 m0 = wr0[0]*h0 + wr1[0]*h1;
    f32x4 m1 = wr0[1]*h0 + wr1[1]*h1;
    f32x4 m2 = wr0[2]*h0 + wr1[2]*h1;
    f32x4 m3 = wr0[3]*h0 + wr1[3]*h1;
    float a0 = m0[0]+m0[1]+m0[2]+m0[3];
    float a1 = m1[0]+m1[1]+m1[2]+m1[3];
    float a2 = m2[0]+m2[1]+m2[2]+m2[3];
    float a3 = m3[0]+m3[1]+m3[2]+m3[3];

    // merged butterfly: 7 shfls -> every lane holds full sum for gate (lane&3)
    float s01 = (lane & 1) ? a1 : a0;
    float o01 = (lane & 1) ? a0 : a1;
    s01 += __shfl_xor(o01, 1);
    float s23 = (lane & 1) ? a3 : a2;
    float o23 = (lane & 1) ? a2 : a3;
    s23 += __shfl_xor(o23, 1);
    float ss = (lane & 2) ? s23 : s01;
    float oo = (lane & 2) ? s01 : s23;
    ss += __shfl_xor(oo, 2);
    ss += __shfl_xor(ss, 4);
    ss += __shfl_xor(ss, 8);
    ss += __shfl_xor(ss, 16);
    ss += __shfl_xor(ss, 32);

    float pre = ss + __shfl(xv_cur, lane & 3) + bias_my;
    bool isg = (lane & 3) == 3;
    float e1 = __expf(isg ? -2.f * pre : -pre);
    float rr = 1.f / (1.f + e1);
    float act = isg ? (2.f * rr - 1.f) : rr;

    float fa = __shfl(act, 1);
    float oa = __shfl(act, 2);
    float ga = __shfl(act, 3);

    if (lane == 0) {
      c = fa * c + act * ga;           // act == input-gate activation on lane 0
      float e2 = __expf(-2.f * c);
      float th = 2.f / (1.f + e2) - 1.f;
      hout = oa * th;
      // publish FIRST (before polls): FIFO vmcnt -> store-ack overlaps poll RT
      unsigned long long pk =
          ((unsigned long long)(unsigned)(t + 1) << 32) | (unsigned long long)__float_as_uint(hout);
      __hip_atomic_store(&Hpack[(size_t)t*DD + hd], pk, __ATOMIC_RELAXED,
                         __HIP_MEMORY_SCOPE_AGENT);
      Hbf[(size_t)t*DD + hd] = (bf16)hout;
    }

    if (t + 1 < TT) {
      // issue polls for h_t now; data arrives while producers finish publishing
      lo = &Hpack[(size_t)t*DD + ((size_t)lane << 2)];
      hi = lo + 256;
      asm volatile("global_load_dwordx4 %0, %4, off sc1\n\t"
                   "global_load_dwordx4 %1, %4, off offset:16 sc1\n\t"
                   "global_load_dwordx4 %2, %5, off sc1\n\t"
                   "global_load_dwordx4 %3, %5, off offset:16 sc1"
                   : "=&v"(p0), "=&v"(p1), "=&v"(p2), "=&v"(p3)
                   : "v"(lo), "v"(hi) : "memory");
      float xv_nxt = 0.f;
      if (lane < 4) {
        const float* xp = &wxp[idxs[t + 1]];
        asm volatile("global_load_dword %0, %1, off" : "=v"(xv_nxt) : "v"(xp) : "memory");
      }
      xv_cur = xv_nxt;   // consumed next iter after vmcnt(0)
    }
  }

  if (lane == 0) { out_tail[hd] = hout; out_tail[DD + hd] = c; }
}

// ---------------- phase 2: logits = Hbf[1024x512] @ Wbf^T[50304x512] + b_out ----------------
__global__ __launch_bounds__(256, 2) void gemm_kernel(
    const bf16* __restrict__ A, const bf16* __restrict__ B,
    const float* __restrict__ bout, float* __restrict__ Cout) {
  __shared__ bf16 As[128*32];
  __shared__ bf16 Bs[128*32];
  const int tid = threadIdx.x;
  const int n0 = blockIdx.x * 128, m0 = blockIdx.y * 128;
  const int w = tid >> 6, l = tid & 63;
  const int wr = w >> 1, wc = w & 1;
  f32x4 acc[4][4] = {};

  for (int k0 = 0; k0 < DD; k0 += 32) {
    #pragma unroll
    for (int c = 0; c < 2; ++c) {
      int j = c*256 + tid;
      int row = j >> 2, kc = (j & 3) << 3;
      gload_lds16(&A[(size_t)(m0 + row)*DD + k0 + kc], (char*)As + (c*4096 + w*1024));
      gload_lds16(&B[(size_t)(n0 + row)*DD + k0 + kc], (char*)Bs + (c*4096 + w*1024));
    }
    __syncthreads();
    bf16x8 af[4], bfr[4];
    #pragma unroll
    for (int mi = 0; mi < 4; ++mi)
      af[mi] = *(const bf16x8*)&As[(wr*64 + mi*16 + (l & 15))*32 + (l >> 4)*8];
    #pragma unroll
    for (int ni = 0; ni < 4; ++ni)
      bfr[ni] = *(const bf16x8*)&Bs[(wc*64 + ni*16 + (l & 15))*32 + (l >> 4)*8];
    #pragma unroll
    for (int mi = 0; mi < 4; ++mi)
      #pragma unroll
      for (int ni = 0; ni < 4; ++ni)
        acc[mi][ni] = __builtin_amdgcn_mfma_f32_16x16x32_bf16(af[mi], bfr[ni], acc[mi][ni], 0, 0, 0);
    __syncthreads();
  }

  #pragma unroll
  for (int mi = 0; mi < 4; ++mi) {
    int rbase = m0 + wr*64 + mi*16 + (l >> 4)*4;
    #pragma unroll
    for (int ni = 0; ni < 4; ++ni) {
      int col = n0 + wc*64 + ni*16 + (l & 15);
      if (col < VV) {
        float bb = bout[col];
        #pragma unroll
        for (int r = 0; r < 4; ++r)
          Cout[(size_t)(rbase + r)*VV + col] = acc[mi][ni][r] + bb;
      }
    }
  }
}

// ---------------- phase 3: in-place row log_softmax ----------------
__global__ __launch_bounds__(256) void lsm_kernel(float* __restrict__ logits) {
  const int t = blockIdx.x, tid = threadIdx.x;
  float* row = logits + (size_t)t*VV;
  float m = -INFINITY, s = 0.f;
  for (int v = tid; v < VV; v += 256) {
    float x = row[v];
    float nm = fmaxf(m, x);
    s = s*expf(m - nm) + expf(x - nm);
    m = nm;
  }
  #pragma unroll
  for (int mask = 1; mask < 64; mask <<= 1) {
    float om = __shfl_xor(m, mask);
    float os = __shfl_xor(s, mask);
    float nm = fmaxf(m, om);
    s = s*expf(m - nm) + os*expf(om - nm);
    m = nm;
  }
  __shared__ float sm[4], ss[4], lse_sh;
  int wv = tid >> 6;
  if ((tid & 63) == 0) { sm[wv] = m; ss[wv] = s; }
  __syncthreads();
  if (tid == 0) {
    float M = sm[0], S = ss[0];
    for (int i2 = 1; i2 < 4; ++i2) {
      float nm = fmaxf(M, sm[i2]);
      S = S*expf(M - nm) + ss[i2]*expf(sm[i2] - nm);
      M = nm;
    }
    lse_sh = M + logf(S);
  }
  __syncthreads();
  float lse = lse_sh;
  for (int v = tid; v < VV; v += 256)
    row[v] -= lse;
}

extern "C" void kernel_launch(void* const* d_in, const int* in_sizes, int n_in,
                              void* d_out, int out_size, void* d_ws, size_t ws_size,
                              hipStream_t stream) {
  const int*   idx  = (const int*)d_in[0];
  const float* Wii  = (const float*)d_in[1];
  const float* Wif  = (const float*)d_in[2];
  const float* Wio  = (const float*)d_in[3];
  const float* Wig  = (const float*)d_in[4];
  const float* Whi  = (const float*)d_in[5];
  const float* Whf  = (const float*)d_in[6];
  const float* Who  = (const float*)d_in[7];
  const float* Whg  = (const float*)d_in[8];
  const float* bi   = (const float*)d_in[9];
  const float* bfv  = (const float*)d_in[10];
  const float* bo   = (const float*)d_in[11];
  const float* bg   = (const float*)d_in[12];
  const float* Wout = (const float*)d_in[13];
  const float* bout = (const float*)d_in[14];
  float* out = (float*)d_out;

  // ws layout:
  //   [0, 51511296)        : Wbf (50304*512 bf16)
  //   [51511296, +4194304) : Hpack (TT*DD u64: stamp<<32 | h bits)
  //   [55705600, +1048576) : Hbf (TT*DD bf16)
  char* ws = (char*)d_ws;
  bf16*  Wbf  = (bf16*)ws;
  unsigned long long* Hpack = (unsigned long long*)(ws + 51511296);
  bf16*  Hbf  = (bf16*)(ws + 55705600);

  hipMemsetAsync(Hpack, 0, (size_t)TT*DD*8, stream);   // fresh stamps every launch
  recur_fused_kernel<<<NBR + WCB, 512, 0, stream>>>(
      idx, Wii, Wif, Wio, Wig, Whi, Whf, Who, Whg, bi, bfv, bo, bg, Wout,
      Hpack, Hbf, Wbf, out + (size_t)TT*VV);
  gemm_kernel<<<dim3(393, 8), 256, 0, stream>>>(Hbf, Wbf, bout, out);
  lsm_kernel<<<TT, 256, 0, stream>>>(out);
}

// Round 10
// 5256.358 us; speedup vs baseline: 1.2026x; 1.2026x over previous
//
#include <hip/hip_runtime.h>
#include <hip/hip_bf16.h>

#define VV 50257
#define DD 512
#define TT 1024
#define VPADN 50304   // 393*128
#define NBR 64        // recurrence blocks, 8 h-dims each
#define WCB 128       // extra blocks doing W_out conversion concurrently

typedef __bf16 bf16;
typedef __attribute__((ext_vector_type(8))) __bf16 bf16x8;
typedef __attribute__((ext_vector_type(4))) __bf16 bf16x4;
typedef __attribute__((ext_vector_type(4))) float f32x4;
typedef __attribute__((ext_vector_type(2))) unsigned int u32x2;

__device__ __forceinline__ void gload_lds16(const void* g, void* l) {
  __builtin_amdgcn_global_load_lds(
      (__attribute__((address_space(1))) void*)(void*)g,
      (__attribute__((address_space(3))) void*)l, 16, 0, 0);
}

// ---------------- phase 1: sequential LSTM recurrence (blocks 0..63)
//                  + W_out f32->bf16 conversion (blocks 64..191, concurrent) --------------
// R8 skeleton (reg weights, 8B/thread polls, LDS h distribution) + pipelined polling:
// 4 same-address loads in flight per thread, check-oldest/reissue rotation (vmcnt(3)),
// deterministic asm issue order [polls, xv, stores] so store-acks never head the queue.
// Custom barrier waits lgkmcnt only. Merged 7-shfl reduce; all-lane xv gather.
__global__ __launch_bounds__(512) __attribute__((amdgpu_waves_per_eu(2, 2)))
void recur_fused_kernel(
    const int* __restrict__ idx,
    const float* __restrict__ Wii, const float* __restrict__ Wif,
    const float* __restrict__ Wio, const float* __restrict__ Wig,
    const float* __restrict__ Whi, const float* __restrict__ Whf,
    const float* __restrict__ Who, const float* __restrict__ Whg,
    const float* __restrict__ bi, const float* __restrict__ bfv,
    const float* __restrict__ bo, const float* __restrict__ bg,
    const float* __restrict__ Wout,
    unsigned long long* __restrict__ Hpack, bf16* __restrict__ Hbf,
    bf16* __restrict__ Wbf, float* __restrict__ out_tail) {
  __shared__ float hsh[2][DD];
  __shared__ int idxs[TT];
  const int b = blockIdx.x, tid = threadIdx.x;

  if (b >= NBR) {            // ---- concurrent W_out conversion ----
    const int wb = b - NBR;
    const size_t nch = (size_t)VPADN * DD / 4;
    for (size_t i = (size_t)wb * 512 + tid; i < nch; i += (size_t)WCB * 512) {
      size_t e = i << 2;
      bf16x4 o;
      if ((e >> 9) < VV) {
        f32x4 x = *(const f32x4*)&Wout[e];
        o[0] = (bf16)x[0]; o[1] = (bf16)x[1]; o[2] = (bf16)x[2]; o[3] = (bf16)x[3];
      } else {
        o[0] = o[1] = o[2] = o[3] = (bf16)0.f;
      }
      *(bf16x4*)&Wbf[e] = o;
    }
    return;
  }

  idxs[tid] = idx[tid];
  idxs[tid + 512] = idx[tid + 512];
  hsh[0][tid] = 0.f;

  const int lane = tid & 63, w = tid >> 6;
  const int hd = (b << 3) + w;
  const int g = lane & 3;

  // per-thread register weights: 4 gates x 2 half-rows (32 VGPRs)
  f32x4 wr0[4], wr1[4];
  {
    #pragma unroll
    for (int gg = 0; gg < 4; ++gg) {
      const float* Wg = (gg == 0) ? Whi : (gg == 1) ? Whf : (gg == 2) ? Who : Whg;
      wr0[gg] = *(const f32x4*)&Wg[(size_t)hd*DD + (lane << 2)];
      wr1[gg] = *(const f32x4*)&Wg[(size_t)hd*DD + 256 + (lane << 2)];
    }
  }
  #pragma unroll
  for (int gg = 0; gg < 4; ++gg) {
    asm volatile("" : "+v"(wr0[gg]));
    asm volatile("" : "+v"(wr1[gg]));
  }

  // every lane gathers its gate's input column (gate = lane&3) for dim hd
  const float* Wx = (g == 0) ? Wii : (g == 1) ? Wif : (g == 2) ? Wio : Wig;
  const float* bx = (g == 0) ? bi : (g == 1) ? bfv : (g == 2) ? bo : bg;
  const float* wxp = &Wx[(size_t)hd * VV];
  const float bias_my = bx[hd];
  const bool own = (tid >= (b << 3)) && (tid < (b << 3) + 8);
  float c = 0.f, hout = 0.f;
  float xv_cur = wxp[idx[0]];
  __syncthreads();   // idxs + hsh[0] ready

  u32x2 q0, q1, q2, q3;
  float xvn;

  for (int t = 0; t < TT; ++t) {
    float* hb_cur = hsh[t & 1];
    float* hb_nxt = hsh[(t + 1) & 1];

    // ---- A: gate dots + merged reduce ----
    const f32x4 h0 = *(const f32x4*)&hb_cur[lane << 2];
    const f32x4 h1 = *(const f32x4*)&hb_cur[256 + (lane << 2)];
    f32x4 m0 = wr0[0]*h0 + wr1[0]*h1;
    f32x4 m1 = wr0[1]*h0 + wr1[1]*h1;
    f32x4 m2 = wr0[2]*h0 + wr1[2]*h1;
    f32x4 m3 = wr0[3]*h0 + wr1[3]*h1;
    float a0 = m0[0]+m0[1]+m0[2]+m0[3];
    float a1 = m1[0]+m1[1]+m1[2]+m1[3];
    float a2 = m2[0]+m2[1]+m2[2]+m2[3];
    float a3 = m3[0]+m3[1]+m3[2]+m3[3];

    float s01 = (lane & 1) ? a1 : a0;
    float o01 = (lane & 1) ? a0 : a1;
    s01 += __shfl_xor(o01, 1);
    float s23 = (lane & 1) ? a3 : a2;
    float o23 = (lane & 1) ? a2 : a3;
    s23 += __shfl_xor(o23, 1);
    float ss = (lane & 2) ? s23 : s01;
    float oo = (lane & 2) ? s01 : s23;
    ss += __shfl_xor(oo, 2);
    ss += __shfl_xor(ss, 4);
    ss += __shfl_xor(ss, 8);
    ss += __shfl_xor(ss, 16);
    ss += __shfl_xor(ss, 32);

    float pre = ss + xv_cur + bias_my;
    bool isg = (g == 3);
    float e1 = __expf(isg ? -2.f * pre : -pre);
    float rr = 1.f / (1.f + e1);
    float act = isg ? (2.f * rr - 1.f) : rr;

    float fa = __shfl(act, 1);
    float oa = __shfl(act, 2);
    float ga = __shfl(act, 3);

    unsigned hu32 = 0, hbits = 0;
    if (lane == 0) {
      c = fa * c + act * ga;           // act == input-gate activation on lane 0
      float e2 = __expf(-2.f * c);
      float th = 2.f / (1.f + e2) - 1.f;
      hout = oa * th;
      hu32 = __float_as_uint(hout);
      bf16 hb16 = (bf16)hout;
      unsigned short us;
      __builtin_memcpy(&us, &hb16, 2);
      hbits = us;
    }

    const unsigned pkhi = (unsigned)(t + 1);

    if (t + 1 < TT) {
      if (lane == 0) hb_nxt[hd] = hout;   // local dims bypass global exchange

      const unsigned long long* src = &Hpack[(size_t)t * DD + tid];
      const float* xp = &wxp[idxs[t + 1]];
      // flight: [p0,p1,p2,p3,xv] -- polls oldest, deterministic order
      asm volatile(
          "s_waitcnt vmcnt(0)\n\t"
          "global_load_dwordx2 %0, %5, off sc1\n\t"
          "global_load_dwordx2 %1, %5, off sc1\n\t"
          "global_load_dwordx2 %2, %5, off sc1\n\t"
          "global_load_dwordx2 %3, %5, off sc1\n\t"
          "global_load_dword  %4, %6, off"
          : "=&v"(q0), "=&v"(q1), "=&v"(q2), "=&v"(q3), "=&v"(xvn)
          : "v"(src), "v"(xp)
          : "memory");
      // publish AFTER polls: store-acks are youngest, never block a check
      if (lane == 0) {
        unsigned long long pk = ((unsigned long long)pkhi << 32) | (unsigned long long)hu32;
        asm volatile(
            "global_store_dwordx2 %0, %1, off sc1\n\t"
            "global_store_short %2, %3, off"
            :: "v"(&Hpack[(size_t)t*DD + hd]), "v"(pk),
               "v"(&Hbf[(size_t)t*DD + hd]), "v"(hbits)
            : "memory");
      }

      bool found = own;
      // 7 vmem outstanding: [p0..p3, xv, pk, hbf]
#define CHK(Q, N) \
      asm volatile("s_waitcnt vmcnt(" #N ")" ::: "memory"); \
      __builtin_amdgcn_sched_barrier(0); \
      if (!found && (Q)[1] == pkhi) { hb_nxt[tid] = __uint_as_float((Q)[0]); found = true; }
#define REI(Q) \
      asm volatile("global_load_dwordx2 %0, %1, off sc1" : "=&v"(Q) : "v"(src) : "memory")

      CHK(q0, 6) REI(q0);
      CHK(q1, 6) REI(q1);
      CHK(q2, 6) REI(q2);
      CHK(q3, 6) REI(q3);
      while (!__all(found)) {
        CHK(q0, 3) REI(q0);
        CHK(q1, 3) REI(q1);
        CHK(q2, 3) REI(q2);
        CHK(q3, 3) REI(q3);
      }
#undef CHK
#undef REI
      // drain in-flight polls (protects q regs from WAW clobber) + keep live
      asm volatile("s_waitcnt vmcnt(0)" ::: "memory");
      __builtin_amdgcn_sched_barrier(0);
      asm volatile("" :: "v"(q0), "v"(q1), "v"(q2), "v"(q3), "v"(xvn));
      xv_cur = xvn;
    }

    // custom barrier: LDS deposits only need lgkmcnt (no vmcnt drain)
    asm volatile("s_waitcnt lgkmcnt(0)\n\ts_barrier" ::: "memory");
  }

  if (lane == 0) {
    Hbf[(size_t)(TT - 1)*DD + hd] = (bf16)hout;
    out_tail[hd] = hout;
    out_tail[DD + hd] = c;
  }
}

// ---------------- phase 2: logits = Hbf[1024x512] @ Wbf^T[50304x512] + b_out ----------------
__global__ __launch_bounds__(256, 2) void gemm_kernel(
    const bf16* __restrict__ A, const bf16* __restrict__ B,
    const float* __restrict__ bout, float* __restrict__ Cout) {
  __shared__ bf16 As[128*32];
  __shared__ bf16 Bs[128*32];
  const int tid = threadIdx.x;
  const int n0 = blockIdx.x * 128, m0 = blockIdx.y * 128;
  const int w = tid >> 6, l = tid & 63;
  const int wr = w >> 1, wc = w & 1;
  f32x4 acc[4][4] = {};

  for (int k0 = 0; k0 < DD; k0 += 32) {
    #pragma unroll
    for (int c = 0; c < 2; ++c) {
      int j = c*256 + tid;
      int row = j >> 2, kc = (j & 3) << 3;
      gload_lds16(&A[(size_t)(m0 + row)*DD + k0 + kc], (char*)As + (c*4096 + w*1024));
      gload_lds16(&B[(size_t)(n0 + row)*DD + k0 + kc], (char*)Bs + (c*4096 + w*1024));
    }
    __syncthreads();
    bf16x8 af[4], bfr[4];
    #pragma unroll
    for (int mi = 0; mi < 4; ++mi)
      af[mi] = *(const bf16x8*)&As[(wr*64 + mi*16 + (l & 15))*32 + (l >> 4)*8];
    #pragma unroll
    for (int ni = 0; ni < 4; ++ni)
      bfr[ni] = *(const bf16x8*)&Bs[(wc*64 + ni*16 + (l & 15))*32 + (l >> 4)*8];
    #pragma unroll
    for (int mi = 0; mi < 4; ++mi)
      #pragma unroll
      for (int ni = 0; ni < 4; ++ni)
        acc[mi][ni] = __builtin_amdgcn_mfma_f32_16x16x32_bf16(af[mi], bfr[ni], acc[mi][ni], 0, 0, 0);
    __syncthreads();
  }

  #pragma unroll
  for (int mi = 0; mi < 4; ++mi) {
    int rbase = m0 + wr*64 + mi*16 + (l >> 4)*4;
    #pragma unroll
    for (int ni = 0; ni < 4; ++ni) {
      int col = n0 + wc*64 + ni*16 + (l & 15);
      if (col < VV) {
        float bb = bout[col];
        #pragma unroll
        for (int r = 0; r < 4; ++r)
          Cout[(size_t)(rbase + r)*VV + col] = acc[mi][ni][r] + bb;
      }
    }
  }
}

// ---------------- phase 3: in-place row log_softmax ----------------
__global__ __launch_bounds__(256) void lsm_kernel(float* __restrict__ logits) {
  const int t = blockIdx.x, tid = threadIdx.x;
  float* row = logits + (size_t)t*VV;
  float m = -INFINITY, s = 0.f;
  for (int v = tid; v < VV; v += 256) {
    float x = row[v];
    float nm = fmaxf(m, x);
    s = s*expf(m - nm) + expf(x - nm);
    m = nm;
  }
  #pragma unroll
  for (int mask = 1; mask < 64; mask <<= 1) {
    float om = __shfl_xor(m, mask);
    float os = __shfl_xor(s, mask);
    float nm = fmaxf(m, om);
    s = s*expf(m - nm) + os*expf(om - nm);
    m = nm;
  }
  __shared__ float sm[4], ss[4], lse_sh;
  int wv = tid >> 6;
  if ((tid & 63) == 0) { sm[wv] = m; ss[wv] = s; }
  __syncthreads();
  if (tid == 0) {
    float M = sm[0], S = ss[0];
    for (int i2 = 1; i2 < 4; ++i2) {
      float nm = fmaxf(M, sm[i2]);
      S = S*expf(M - nm) + ss[i2]*expf(sm[i2] - nm);
      M = nm;
    }
    lse_sh = M + logf(S);
  }
  __syncthreads();
  float lse = lse_sh;
  for (int v = tid; v < VV; v += 256)
    row[v] -= lse;
}

extern "C" void kernel_launch(void* const* d_in, const int* in_sizes, int n_in,
                              void* d_out, int out_size, void* d_ws, size_t ws_size,
                              hipStream_t stream) {
  const int*   idx  = (const int*)d_in[0];
  const float* Wii  = (const float*)d_in[1];
  const float* Wif  = (const float*)d_in[2];
  const float* Wio  = (const float*)d_in[3];
  const float* Wig  = (const float*)d_in[4];
  const float* Whi  = (const float*)d_in[5];
  const float* Whf  = (const float*)d_in[6];
  const float* Who  = (const float*)d_in[7];
  const float* Whg  = (const float*)d_in[8];
  const float* bi   = (const float*)d_in[9];
  const float* bfv  = (const float*)d_in[10];
  const float* bo   = (const float*)d_in[11];
  const float* bg   = (const float*)d_in[12];
  const float* Wout = (const float*)d_in[13];
  const float* bout = (const float*)d_in[14];
  float* out = (float*)d_out;

  // ws layout:
  //   [0, 51511296)        : Wbf (50304*512 bf16)
  //   [51511296, +4194304) : Hpack (TT*DD u64: stamp<<32 | h bits)
  //   [55705600, +1048576) : Hbf (TT*DD bf16)
  char* ws = (char*)d_ws;
  bf16*  Wbf  = (bf16*)ws;
  unsigned long long* Hpack = (unsigned long long*)(ws + 51511296);
  bf16*  Hbf  = (bf16*)(ws + 55705600);

  hipMemsetAsync(Hpack, 0, (size_t)TT*DD*8, stream);   // fresh stamps every launch
  recur_fused_kernel<<<NBR + WCB, 512, 0, stream>>>(
      idx, Wii, Wif, Wio, Wig, Whi, Whf, Who, Whg, bi, bfv, bo, bg, Wout,
      Hpack, Hbf, Wbf, out + (size_t)TT*VV);
  gemm_kernel<<<dim3(393, 8), 256, 0, stream>>>(Hbf, Wbf, bout, out);
  lsm_kernel<<<TT, 256, 0, stream>>>(out);
}

// Round 12
// 1980.453 us; speedup vs baseline: 3.1920x; 2.6541x over previous
//
#include <hip/hip_runtime.h>
#include <hip/hip_bf16.h>

#define VV 50257
#define DD 512
#define TT 1024
#define VPADN 50304   // 393*128
#define NBR 64        // recurrence blocks, 8 h-dims each
#define WCB 128       // extra blocks doing W_out conversion concurrently

typedef __bf16 bf16;
typedef __attribute__((ext_vector_type(8))) __bf16 bf16x8;
typedef __attribute__((ext_vector_type(4))) __bf16 bf16x4;
typedef __attribute__((ext_vector_type(4))) float f32x4;

__device__ __forceinline__ void gload_lds16(const void* g, void* l) {
  __builtin_amdgcn_global_load_lds(
      (__attribute__((address_space(1))) void*)(void*)g,
      (__attribute__((address_space(3))) void*)l, 16, 0, 0);
}

// ---------------- phase 1: sequential LSTM recurrence (blocks 0..63)
//                  + W_out f32->bf16 conversion (blocks 64..191, concurrent) --------------
// (R8 structure, verbatim -- best verified: 1790us, absmax 7.6e-6)
__global__ __launch_bounds__(512) __attribute__((amdgpu_waves_per_eu(2, 2)))
void recur_fused_kernel(
    const int* __restrict__ idx,
    const float* __restrict__ Wii, const float* __restrict__ Wif,
    const float* __restrict__ Wio, const float* __restrict__ Wig,
    const float* __restrict__ Whi, const float* __restrict__ Whf,
    const float* __restrict__ Who, const float* __restrict__ Whg,
    const float* __restrict__ bi, const float* __restrict__ bfv,
    const float* __restrict__ bo, const float* __restrict__ bg,
    const float* __restrict__ Wout,
    unsigned long long* __restrict__ Hpack, bf16* __restrict__ Hbf,
    bf16* __restrict__ Wbf, float* __restrict__ out_tail) {
  __shared__ float hsh[2][DD];
  __shared__ int idxs[TT];
  const int b = blockIdx.x, tid = threadIdx.x;

  if (b >= NBR) {            // ---- concurrent W_out conversion ----
    const int wb = b - NBR;
    const size_t nch = (size_t)VPADN * DD / 4;
    for (size_t i = (size_t)wb * 512 + tid; i < nch; i += (size_t)WCB * 512) {
      size_t e = i << 2;
      bf16x4 o;
      if ((e >> 9) < VV) {
        f32x4 x = *(const f32x4*)&Wout[e];
        o[0] = (bf16)x[0]; o[1] = (bf16)x[1]; o[2] = (bf16)x[2]; o[3] = (bf16)x[3];
      } else {
        o[0] = o[1] = o[2] = o[3] = (bf16)0.f;
      }
      *(bf16x4*)&Wbf[e] = o;
    }
    return;
  }

  idxs[tid] = idx[tid];
  idxs[tid + 512] = idx[tid + 512];

  const int lane = tid & 63, w = tid >> 6;
  const int hd = (b << 3) + w;

  // per-thread register weights: 4 gates x 2 half-rows (32 VGPRs)
  f32x4 wr0[4], wr1[4];
  {
    #pragma unroll
    for (int gg = 0; gg < 4; ++gg) {
      const float* Wg = (gg == 0) ? Whi : (gg == 1) ? Whf : (gg == 2) ? Who : Whg;
      wr0[gg] = *(const f32x4*)&Wg[(size_t)hd*DD + (lane << 2)];
      wr1[gg] = *(const f32x4*)&Wg[(size_t)hd*DD + 256 + (lane << 2)];
    }
  }
  #pragma unroll
  for (int gg = 0; gg < 4; ++gg) {
    asm volatile("" : "+v"(wr0[gg]));
    asm volatile("" : "+v"(wr1[gg]));
  }

  // lanes 0..3: gate-input gather pointers (gate = lane)
  const float* wxp = nullptr;
  float bias = 0.f;
  if (lane < 4) {
    const float* Wx = (lane == 0) ? Wii : (lane == 1) ? Wif : (lane == 2) ? Wio : Wig;
    const float* bx = (lane == 0) ? bi : (lane == 1) ? bfv : (lane == 2) ? bo : bg;
    wxp = &Wx[(size_t)hd * VV];
    bias = bx[hd];
  }
  float c = 0.f, hout = 0.f;
  __syncthreads();   // idxs ready

  for (int t = 0; t < TT; ++t) {
    float xv = 0.f;
    if (lane < 4) xv = wxp[idxs[t]] + bias;   // overlaps discovery (max, not sum)

    float* hb = hsh[t & 1];
    if (t > 0) {
      const unsigned long long* src = &Hpack[(size_t)(t-1)*DD + tid];
      unsigned long long v;
      do {
        asm volatile("global_load_dwordx2 %0, %1, off sc1\n\t"
                     "s_waitcnt vmcnt(0)"
                     : "=v"(v) : "v"(src) : "memory");
      } while (__builtin_expect((unsigned)(v >> 32) != (unsigned)t, 0));
      hb[tid] = __uint_as_float((unsigned)v);
    } else {
      hb[tid] = 0.f;
    }
    __syncthreads();   // single barrier per step (hsh double-buffered)

    const f32x4 h0 = *(const f32x4*)&hb[lane << 2];
    const f32x4 h1 = *(const f32x4*)&hb[256 + (lane << 2)];
    f32x4 m0 = wr0[0]*h0 + wr1[0]*h1;
    f32x4 m1 = wr0[1]*h0 + wr1[1]*h1;
    f32x4 m2 = wr0[2]*h0 + wr1[2]*h1;
    f32x4 m3 = wr0[3]*h0 + wr1[3]*h1;
    float a0 = m0[0]+m0[1]+m0[2]+m0[3];
    float a1 = m1[0]+m1[1]+m1[2]+m1[3];
    float a2 = m2[0]+m2[1]+m2[2]+m2[3];
    float a3 = m3[0]+m3[1]+m3[2]+m3[3];
    #pragma unroll
    for (int mask = 1; mask < 64; mask <<= 1) {
      a0 += __shfl_xor(a0, mask);
      a1 += __shfl_xor(a1, mask);
      a2 += __shfl_xor(a2, mask);
      a3 += __shfl_xor(a3, mask);
    }

    // lanes 0..3 compute their gate's activation
    float myacc = (lane == 0) ? a0 : (lane == 1) ? a1 : (lane == 2) ? a2 : a3;
    float pre = myacc + xv;
    bool isg = (lane == 3);
    float e1 = __expf(isg ? -2.f * pre : -pre);
    float rr = 1.f / (1.f + e1);
    float act = isg ? (2.f * rr - 1.f) : rr;

    float ia = __shfl(act, 0);
    float fa = __shfl(act, 1);
    float oa = __shfl(act, 2);
    float ga = __shfl(act, 3);

    if (lane == 0) {
      c = fa * c + ia * ga;
      float e2 = __expf(-2.f * c);
      float th = 2.f / (1.f + e2) - 1.f;
      hout = oa * th;
      unsigned long long pk =
          ((unsigned long long)(unsigned)(t + 1) << 32) |
          (unsigned long long)__float_as_uint(hout);
      __hip_atomic_store(&Hpack[(size_t)t*DD + hd], pk, __ATOMIC_RELAXED,
                         __HIP_MEMORY_SCOPE_AGENT);
      Hbf[(size_t)t*DD + hd] = (bf16)hout;
      if (t == TT - 1) { out_tail[hd] = hout; out_tail[DD + hd] = c; }
    }
  }
}

// ---------------- phase 2: logits = Hbf[1024x512] @ Wbf^T[50304x512] + b_out ----------------
// Epilogue v2: per-wave LDS transpose staging -> 256B-contiguous dwordx4 row writes.
__global__ __launch_bounds__(256, 2) void gemm_kernel(
    const bf16* __restrict__ A, const bf16* __restrict__ B,
    const float* __restrict__ bout, float* __restrict__ Cout) {
  __shared__ bf16 As[128*32];
  __shared__ bf16 Bs[128*32];
  __shared__ float Cs[4][16][72];   // per-wave 16x64 staging, pad 72 (bank de-alias)
  const int tid = threadIdx.x;
  const int n0 = blockIdx.x * 128, m0 = blockIdx.y * 128;
  const int w = tid >> 6, l = tid & 63;
  const int wr = w >> 1, wc = w & 1;
  f32x4 acc[4][4] = {};

  for (int k0 = 0; k0 < DD; k0 += 32) {
    #pragma unroll
    for (int c = 0; c < 2; ++c) {
      int j = c*256 + tid;
      int row = j >> 2, kc = (j & 3) << 3;
      gload_lds16(&A[(size_t)(m0 + row)*DD + k0 + kc], (char*)As + (c*4096 + w*1024));
      gload_lds16(&B[(size_t)(n0 + row)*DD + k0 + kc], (char*)Bs + (c*4096 + w*1024));
    }
    __syncthreads();
    bf16x8 af[4], bfr[4];
    #pragma unroll
    for (int mi = 0; mi < 4; ++mi)
      af[mi] = *(const bf16x8*)&As[(wr*64 + mi*16 + (l & 15))*32 + (l >> 4)*8];
    #pragma unroll
    for (int ni = 0; ni < 4; ++ni)
      bfr[ni] = *(const bf16x8*)&Bs[(wc*64 + ni*16 + (l & 15))*32 + (l >> 4)*8];
    #pragma unroll
    for (int mi = 0; mi < 4; ++mi)
      #pragma unroll
      for (int ni = 0; ni < 4; ++ni)
        acc[mi][ni] = __builtin_amdgcn_mfma_f32_16x16x32_bf16(af[mi], bfr[ni], acc[mi][ni], 0, 0, 0);
    __syncthreads();
  }

  // bias per output-column group (ni)
  float bbv[4];
  #pragma unroll
  for (int ni = 0; ni < 4; ++ni) {
    int col = n0 + wc*64 + ni*16 + (l & 15);
    bbv[ni] = (col < VV) ? bout[col] : 0.f;
  }

  #pragma unroll
  for (int mi = 0; mi < 4; ++mi) {
    // stage this mi's 16x64 wave-tile into LDS (per-wave private region)
    #pragma unroll
    for (int ni = 0; ni < 4; ++ni)
      #pragma unroll
      for (int r = 0; r < 4; ++r)
        Cs[w][(l >> 4)*4 + r][ni*16 + (l & 15)] = acc[mi][ni][r] + bbv[ni];
    // LDS per-wave in-order: reads below see the writes above
    const int rbase = m0 + wr*64 + mi*16;
    #pragma unroll
    for (int i = 0; i < 4; ++i) {
      int idx2 = i*64 + l;
      int row = idx2 >> 4, quad = idx2 & 15;
      int col = n0 + wc*64 + quad*4;
      f32x4 v = *(const f32x4*)&Cs[w][row][quad*4];
      float* dst = &Cout[(size_t)(rbase + row)*VV + col];
      if (col + 3 < VV) {
        asm volatile("global_store_dwordx4 %0, %1, off"
                     :: "v"(dst), "v"(v) : "memory");
      } else {
        #pragma unroll
        for (int e = 0; e < 4; ++e)
          if (col + e < VV) dst[e] = v[e];
      }
    }
  }
}

// ---------------- phase 3: in-place row log_softmax (512 thr, aligned float4) ------------
__global__ __launch_bounds__(512) void lsm_kernel(float* __restrict__ logits) {
  const int t = blockIdx.x, tid = threadIdx.x;
  float* row = logits + (size_t)t*VV;
  const size_t base = (size_t)t * VV;
  const int head = (int)((4 - (base & 3)) & 3);       // scalars before 16B alignment
  const int nvec = (VV - head) >> 2;
  const int tail0 = head + (nvec << 2);               // first tail element index

  float m = -INFINITY, s = 0.f;
  if (tid < head) {
    float x = row[tid];
    m = x; s = 1.f;
  } else if (tid >= 508 && (tail0 + (tid - 508)) < VV) {
    float x = row[tail0 + (tid - 508)];
    m = x; s = 1.f;
  }
  for (int i = tid; i < nvec; i += 512) {
    f32x4 x = *(const f32x4*)&row[head + (i << 2)];
    float mx = fmaxf(fmaxf(x[0], x[1]), fmaxf(x[2], x[3]));
    float nm = fmaxf(m, mx);
    s = s*__expf(m - nm) + __expf(x[0] - nm) + __expf(x[1] - nm)
        + __expf(x[2] - nm) + __expf(x[3] - nm);
    m = nm;
  }
  #pragma unroll
  for (int mask = 1; mask < 64; mask <<= 1) {
    float om = __shfl_xor(m, mask);
    float os = __shfl_xor(s, mask);
    float nm = fmaxf(m, om);
    s = s*__expf(m - nm) + os*__expf(om - nm);
    m = nm;
  }
  __shared__ float sm[8], ss[8], lse_sh;
  int wv = tid >> 6;
  if ((tid & 63) == 0) { sm[wv] = m; ss[wv] = s; }
  __syncthreads();
  if (tid == 0) {
    float M = sm[0], S = ss[0];
    for (int i2 = 1; i2 < 8; ++i2) {
      float nm = fmaxf(M, sm[i2]);
      S = S*__expf(M - nm) + ss[i2]*__expf(sm[i2] - nm);
      M = nm;
    }
    lse_sh = M + logf(S);
  }
  __syncthreads();
  float lse = lse_sh;
  if (tid < head) row[tid] -= lse;
  else if (tid >= 508 && (tail0 + (tid - 508)) < VV) row[tail0 + (tid - 508)] -= lse;
  for (int i = tid; i < nvec; i += 512) {
    float* p = &row[head + (i << 2)];
    f32x4 x = *(const f32x4*)p;
    x[0] -= lse; x[1] -= lse; x[2] -= lse; x[3] -= lse;
    *(f32x4*)p = x;
  }
}

extern "C" void kernel_launch(void* const* d_in, const int* in_sizes, int n_in,
                              void* d_out, int out_size, void* d_ws, size_t ws_size,
                              hipStream_t stream) {
  const int*   idx  = (const int*)d_in[0];
  const float* Wii  = (const float*)d_in[1];
  const float* Wif  = (const float*)d_in[2];
  const float* Wio  = (const float*)d_in[3];
  const float* Wig  = (const float*)d_in[4];
  const float* Whi  = (const float*)d_in[5];
  const float* Whf  = (const float*)d_in[6];
  const float* Who  = (const float*)d_in[7];
  const float* Whg  = (const float*)d_in[8];
  const float* bi   = (const float*)d_in[9];
  const float* bfv  = (const float*)d_in[10];
  const float* bo   = (const float*)d_in[11];
  const float* bg   = (const float*)d_in[12];
  const float* Wout = (const float*)d_in[13];
  const float* bout = (const float*)d_in[14];
  float* out = (float*)d_out;

  // ws layout:
  //   [0, 51511296)        : Wbf (50304*512 bf16)
  //   [51511296, +4194304) : Hpack (TT*DD u64: stamp<<32 | h bits)
  //   [55705600, +1048576) : Hbf (TT*DD bf16)
  char* ws = (char*)d_ws;
  bf16*  Wbf  = (bf16*)ws;
  unsigned long long* Hpack = (unsigned long long*)(ws + 51511296);
  bf16*  Hbf  = (bf16*)(ws + 55705600);

  hipMemsetAsync(Hpack, 0, (size_t)TT*DD*8, stream);   // fresh stamps every launch
  recur_fused_kernel<<<NBR + WCB, 512, 0, stream>>>(
      idx, Wii, Wif, Wio, Wig, Whi, Whf, Who, Whg, bi, bfv, bo, bg, Wout,
      Hpack, Hbf, Wbf, out + (size_t)TT*VV);
  gemm_kernel<<<dim3(393, 8), 256, 0, stream>>>(Hbf, Wbf, bout, out);
  lsm_kernel<<<TT, 512, 0, stream>>>(out);
}